// Round 11
// baseline (281.837 us; speedup 1.0000x reference)
//
#include <hip/hip_runtime.h>

#define T_SEQ 2048
#define HID 4096
#define NH 32
#define NKV 8
#define HD 128
#define KDIM 4096

typedef unsigned short u16;
typedef signed char s8;
typedef __attribute__((ext_vector_type(4))) float f32x4;
typedef __attribute__((ext_vector_type(4))) int i32x4;
typedef __attribute__((ext_vector_type(16))) int i32x16;
typedef __attribute__((ext_vector_type(2))) unsigned int u32x2;
typedef __attribute__((ext_vector_type(8))) short s16x8;
typedef __attribute__((ext_vector_type(4))) short s16x4;
typedef __attribute__((ext_vector_type(8))) __bf16 bf16x8;
typedef __attribute__((ext_vector_type(8))) _Float16 f16x8;

static __device__ __forceinline__ u16 f2bf(float f) {
    __bf16 b = (__bf16)f;
    return __builtin_bit_cast(unsigned short, b);
}
static __device__ __forceinline__ float bf2f(u16 b) {
    unsigned u = ((unsigned)b) << 16;
    return __builtin_bit_cast(float, u);
}
static __device__ __forceinline__ __bf16 bfbits(u16 b) {
    return __builtin_bit_cast(__bf16, b);
}
static __device__ __forceinline__ u16 f2h(float f) {
    _Float16 h = (_Float16)f;
    return __builtin_bit_cast(unsigned short, h);
}

typedef __attribute__((address_space(1))) const void gas_t;
typedef __attribute__((address_space(3))) void las_t;
static __device__ __forceinline__ void gll16(const void* g, void* l) {
    __builtin_amdgcn_global_load_lds((gas_t*)g, (las_t*)l, 16, 0, 0);
}

// ---- fused pre-pass: trig tables | activation int4-quant | QKV weight pack --
__global__ __launch_bounds__(256) void k_pre(const int* __restrict__ pos,
        const float* __restrict__ x, const int* __restrict__ wq,
        const int* __restrict__ wk, const int* __restrict__ wv,
        float* __restrict__ ctab, float* __restrict__ stab,
        s8* __restrict__ a8, float* __restrict__ srow,
        s8* __restrict__ q8, s8* __restrict__ k8, s8* __restrict__ v8) {
    int b = blockIdx.x, tid = threadIdx.x;
    if (b < 512) {
        int idx = b * 256 + tid;
        int t = idx >> 6, d = idx & 63;
        float p = (float)pos[t];
        float inv = (float)pow(10000.0, -(double)d / 64.0);
        float ang = p * inv;
        double dsn, dcs;
        sincos((double)ang, &dsn, &dcs);
        ctab[idx] = (float)dcs;
        stab[idx] = (float)dsn;
    } else if (b < 512 + 2048) {
        int row = b - 512;
        const float* xr = x + (size_t)row * HID;
        f32x4 v[4];
        float amax = 0.f;
#pragma unroll
        for (int i = 0; i < 4; ++i) {
            v[i] = *(const f32x4*)(xr + i * 1024 + tid * 4);
#pragma unroll
            for (int j = 0; j < 4; ++j) amax = fmaxf(amax, fabsf(v[i][j]));
        }
#pragma unroll
        for (int off = 32; off >= 1; off >>= 1)
            amax = fmaxf(amax, __shfl_xor(amax, off));
        __shared__ float red[4];
        if ((tid & 63) == 0) red[tid >> 6] = amax;
        __syncthreads();
        amax = fmaxf(fmaxf(red[0], red[1]), fmaxf(red[2], red[3]));
        float s = fmaxf(amax / 7.f, 1e-8f);
        if (tid == 0) srow[row] = s;
        int* qr = (int*)(a8 + (size_t)row * HID);
#pragma unroll
        for (int i = 0; i < 4; ++i) {
            int p = 0;
#pragma unroll
            for (int j = 0; j < 4; ++j) {
                float q = rintf(v[i][j] / s);
                q = fminf(fmaxf(q, -8.f), 7.f);
                p |= ((int)q & 0xff) << (8 * j);
            }
            qr[i * 256 + tid] = p;
        }
    } else {
        size_t i = ((size_t)(b - 2560) * 256 + tid) * 16;
        const int* src; s8* dst; size_t off;
        if (i < 16777216) { src = wq; dst = q8; off = i; }
        else if (i < 20971520) { src = wk; dst = k8; off = i - 16777216; }
        else { src = wv; dst = v8; off = i - 20971520; }
        i32x4 o;
#pragma unroll
        for (int j = 0; j < 4; ++j) {
            i32x4 v = *(const i32x4*)(src + off + j * 4);
            o[j] = (v[0] & 0xff) | ((v[1] & 0xff) << 8) |
                   ((v[2] & 0xff) << 16) | (v[3] << 24);
        }
        *(i32x4*)(dst + off) = o;
    }
}

// ---------------- unified QKV int8 GEMM, 32x32x32 MFMA, dbuf pipeline -------
__global__ __launch_bounds__(256) void k_qkv(const s8* __restrict__ A,
        const s8* __restrict__ Wq, const s8* __restrict__ Wk,
        const s8* __restrict__ Wv, const float* __restrict__ sRow,
        const float* __restrict__ sq, const float* __restrict__ sk,
        const float* __restrict__ sv, float* __restrict__ qout,
        float* __restrict__ kout, u16* __restrict__ voutf) {
    __shared__ __align__(16) s8 sA[2][16384], sB[2][16384];
    int tid = threadIdx.x;
    int by = blockIdx.y;
    int mode = by < 32 ? 0 : (by < 40 ? 1 : 2);
    const s8* W = mode == 0 ? Wq : (mode == 1 ? Wk : Wv);
    const float* sCol = mode == 0 ? sq : (mode == 1 ? sk : sv);
    int bcolb = mode == 0 ? by : (mode == 1 ? by - 32 : by - 40);
    int brow = blockIdx.x * 128, bcol = bcolb * 128;
    const int K = KDIM;
    int wid = tid >> 6, lane = tid & 63;
    int wr = (wid >> 1) * 64, wc = (wid & 1) * 64;
    int l31 = lane & 31, hc = lane >> 5;
    i32x16 acc[2][2] = {};
    auto stage = [&](int buf, int k0) {
#pragma unroll
        for (int j = 0; j < 4; ++j) {
            int base = wid * 1024 + j * 4096;
            int o = base + lane * 16;
            int r = o >> 7;
            int c = (o & 127) ^ ((r & 7) << 4);
            gll16(A + (size_t)(brow + r) * K + (k0 + c), (char*)sA[buf] + base);
            gll16(W + (size_t)(bcol + r) * K + (k0 + c), (char*)sB[buf] + base);
        }
    };
    stage(0, 0);
    asm volatile("s_waitcnt vmcnt(0)" ::: "memory");
    __syncthreads();
    int cur = 0;
    for (int k0 = 0; k0 < K; k0 += 128) {
        if (k0 + 128 < K) stage(cur ^ 1, k0 + 128);
#pragma unroll
        for (int kk = 0; kk < 4; ++kk) {
            i32x4 af[2], bf[2];
#pragma unroll
            for (int f = 0; f < 2; ++f) {
                int r = wr + f * 32 + l31;
                int sl = ((kk * 2 + hc) ^ (r & 7)) * 16;
                af[f] = *(const i32x4*)&sA[cur][r * 128 + sl];
                int r2 = wc + f * 32 + l31;
                int sl2 = ((kk * 2 + hc) ^ (r2 & 7)) * 16;
                bf[f] = *(const i32x4*)&sB[cur][r2 * 128 + sl2];
            }
#pragma unroll
            for (int fm = 0; fm < 2; ++fm)
#pragma unroll
                for (int fn = 0; fn < 2; ++fn)
                    acc[fm][fn] = __builtin_amdgcn_mfma_i32_32x32x32_i8(
                        af[fm], bf[fn], acc[fm][fn], 0, 0, 0);
        }
        asm volatile("s_waitcnt vmcnt(0)" ::: "memory");
        __syncthreads();
        cur ^= 1;
    }
    // C/D 32x32: col = lane&31, row = (reg&3) + 8*(reg>>2) + 4*(lane>>5)
#pragma unroll
    for (int fm = 0; fm < 2; ++fm)
#pragma unroll
        for (int fn = 0; fn < 2; ++fn) {
            int col = bcol + wc + fn * 32 + l31;
            float scl = sCol[col];
#pragma unroll
            for (int g = 0; g < 4; ++g) {
                int row0 = brow + wr + fm * 32 + g * 8 + 4 * hc;
                if (mode == 0) {
#pragma unroll
                    for (int t = 0; t < 4; ++t)
                        qout[(size_t)(row0 + t) * HID + col] =
                            (float)acc[fm][fn][g * 4 + t] * sRow[row0 + t] * scl;
                } else if (mode == 1) {
#pragma unroll
                    for (int t = 0; t < 4; ++t)
                        kout[(size_t)(row0 + t) * (NKV * HD) + col] =
                            (float)acc[fm][fn][g * 4 + t] * sRow[row0 + t] * scl;
                } else {
                    int kvh = col >> 7, d = col & 127;
                    int nn = d >> 4, lrv = d & 15;
                    int kt = row0 >> 6, rem = row0 & 63;
                    int kc = rem >> 5, lcv = (rem & 31) >> 3, j0 = rem & 7;
                    size_t base =
                        ((((size_t)(kvh * 32 + kt) * 2 + kc) * 8 + nn) * 64 +
                         lcv * 16 + lrv) * 8 + j0;
                    s16x4 hh;
#pragma unroll
                    for (int t = 0; t < 4; ++t) {
                        float val =
                            (float)acc[fm][fn][g * 4 + t] * sRow[row0 + t] * scl;
                        hh[t] = (short)f2h(val);
                    }
                    *(s16x4*)(voutf + base) = hh;
                }
            }
        }
}

// ---------------- O-proj int8 GEMM, 32x32x32 MFMA, dbuf pipeline ------------
__global__ __launch_bounds__(256) void k_gemm8(const s8* __restrict__ A,
        const s8* __restrict__ W, const float* __restrict__ sRow,
        const float* __restrict__ sCol, float* __restrict__ outp) {
    __shared__ __align__(16) s8 sA[2][16384], sB[2][16384];
    int tid = threadIdx.x;
    int brow = blockIdx.x * 128, bcol = blockIdx.y * 128;
    const int K = KDIM;
    int wid = tid >> 6, lane = tid & 63;
    int wr = (wid >> 1) * 64, wc = (wid & 1) * 64;
    int l31 = lane & 31, hc = lane >> 5;
    i32x16 acc[2][2] = {};
    auto stage = [&](int buf, int k0) {
#pragma unroll
        for (int j = 0; j < 4; ++j) {
            int base = wid * 1024 + j * 4096;
            int o = base + lane * 16;
            int r = o >> 7;
            int c = (o & 127) ^ ((r & 7) << 4);
            gll16(A + (size_t)(brow + r) * K + (k0 + c), (char*)sA[buf] + base);
            gll16(W + (size_t)(bcol + r) * K + (k0 + c), (char*)sB[buf] + base);
        }
    };
    stage(0, 0);
    asm volatile("s_waitcnt vmcnt(0)" ::: "memory");
    __syncthreads();
    int cur = 0;
    for (int k0 = 0; k0 < K; k0 += 128) {
        if (k0 + 128 < K) stage(cur ^ 1, k0 + 128);
#pragma unroll
        for (int kk = 0; kk < 4; ++kk) {
            i32x4 af[2], bf[2];
#pragma unroll
            for (int f = 0; f < 2; ++f) {
                int r = wr + f * 32 + l31;
                int sl = ((kk * 2 + hc) ^ (r & 7)) * 16;
                af[f] = *(const i32x4*)&sA[cur][r * 128 + sl];
                int r2 = wc + f * 32 + l31;
                int sl2 = ((kk * 2 + hc) ^ (r2 & 7)) * 16;
                bf[f] = *(const i32x4*)&sB[cur][r2 * 128 + sl2];
            }
#pragma unroll
            for (int fm = 0; fm < 2; ++fm)
#pragma unroll
                for (int fn = 0; fn < 2; ++fn)
                    acc[fm][fn] = __builtin_amdgcn_mfma_i32_32x32x32_i8(
                        af[fm], bf[fn], acc[fm][fn], 0, 0, 0);
        }
        asm volatile("s_waitcnt vmcnt(0)" ::: "memory");
        __syncthreads();
        cur ^= 1;
    }
#pragma unroll
    for (int fm = 0; fm < 2; ++fm)
#pragma unroll
        for (int fn = 0; fn < 2; ++fn) {
            int col = bcol + wc + fn * 32 + l31;
            float scl = sCol[col];
#pragma unroll
            for (int g = 0; g < 4; ++g) {
                int row0 = brow + wr + fm * 32 + g * 8 + 4 * hc;
#pragma unroll
                for (int t = 0; t < 4; ++t)
                    outp[(size_t)(row0 + t) * HID + col] =
                        (float)acc[fm][fn][g * 4 + t] * sRow[row0 + t] * scl;
            }
        }
}

// ---------------- RoPE on K only -> fragment-ordered hi/lo bf16 -------------
__global__ __launch_bounds__(256) void k_ropek(const float* __restrict__ kf,
        const float* __restrict__ ctab, const float* __restrict__ stab,
        u16* __restrict__ khf, u16* __restrict__ klf) {
    int t = blockIdx.x, tid = threadIdx.x;
    int kt = t >> 6, rem = t & 63, cblk = rem >> 4, lrk = rem & 15;
    for (int idx = tid; idx < NKV * 64; idx += 256) {
        int kh = idx >> 6, d = idx & 63;
        float cs = ctab[t * 64 + d], sn = stab[t * 64 + d];
        size_t base = (size_t)t * (NKV * HD) + kh * HD;
        float x1 = kf[base + d], x2 = kf[base + d + 64];
        float r1 = x1 * cs - x2 * sn;
        float r2 = x2 * cs + x1 * sn;
        size_t tb = (((size_t)(kh * 32 + kt) * 4 + cblk) * 4) * 512;
#pragma unroll
        for (int half = 0; half < 2; ++half) {
            int x = d + half * 64;
            float rv = half ? r2 : r1;
            int dcx = x >> 5, lcx = (x & 31) >> 3, jx = x & 7;
            size_t ii = tb + (size_t)dcx * 512 + (lcx * 16 + lrk) * 8 + jx;
            u16 hb = f2bf(rv);
            khf[ii] = hb;
            klf[ii] = f2bf(rv - bf2f(hb));
        }
    }
}

// ---------------- GQA causal flash attention (unchanged from R10) ------------
__global__ __launch_bounds__(512, 4) void k_attn(float* __restrict__ qf,
        const u16* __restrict__ khf, const u16* __restrict__ klf,
        const u16* __restrict__ vf,
        const float* __restrict__ ctab, const float* __restrict__ stab) {
    int bid = blockIdx.x;
    int kvh = bid & 7;
    int h = kvh * 4 + ((bid >> 3) & 3);
    int sidx = bid >> 5;
    int bx = sidx < 8 ? sidx : 23 - sidx;
    int tid = threadIdx.x, wid = tid >> 6, lane = tid & 63;
    int lr = lane & 15, lc = lane >> 4;
    int q0 = bx * 128 + wid * 16, q_hi = q0 + 15;
    __shared__ __align__(16) u16 smem[37888];
    u16* pb = smem + 32768 + wid * 640;
    const float SCL = 0.12751744f;
    size_t kvbase = (size_t)kvh * 32 * 8192;
    auto stageK = [&](int kt) {
        const char* gk = (const char*)(khf + kvbase + (size_t)kt * 8192);
        const char* gl = (const char*)(klf + kvbase + (size_t)kt * 8192);
#pragma unroll
        for (int j = 0; j < 4; ++j) {
            int c = wid * 4 + j;
            int sel = c >> 4;
            int inner = (c & 15) * 1024;
            gll16((sel ? gl : gk) + inner + lane * 16,
                  (char*)smem + sel * 16384 + inner);
        }
    };
    auto stageV = [&](int kt, int buf) {
        const char* gv = (const char*)(vf + kvbase + (size_t)kt * 8192);
#pragma unroll
        for (int j = 0; j < 2; ++j) {
            int c = wid * 2 + j;
            gll16(gv + c * 1024 + lane * 16,
                  (char*)smem + 32768 + buf * 16384 + c * 1024);
        }
    };
    bf16x8 aqh[4], aql[4];
    {
        const float* qrow = qf + (size_t)(q0 + lr) * HID + h * HD;
        const float* ct = ctab + (size_t)(q0 + lr) * 64 + lc * 8;
        const float* st = stab + (size_t)(q0 + lr) * 64 + lc * 8;
        float qv[4][8];
#pragma unroll
        for (int dc = 0; dc < 4; ++dc) {
            f32x4 a = *(const f32x4*)(qrow + dc * 32 + lc * 8);
            f32x4 b = *(const f32x4*)(qrow + dc * 32 + lc * 8 + 4);
#pragma unroll
            for (int j = 0; j < 4; ++j) { qv[dc][j] = a[j]; qv[dc][j + 4] = b[j]; }
        }
        float cs[2][8], sn[2][8];
#pragma unroll
        for (int hf = 0; hf < 2; ++hf) {
            f32x4 c0 = *(const f32x4*)(ct + hf * 32);
            f32x4 c1 = *(const f32x4*)(ct + hf * 32 + 4);
            f32x4 s0 = *(const f32x4*)(st + hf * 32);
            f32x4 s1 = *(const f32x4*)(st + hf * 32 + 4);
#pragma unroll
            for (int j = 0; j < 4; ++j) {
                cs[hf][j] = c0[j]; cs[hf][j + 4] = c1[j];
                sn[hf][j] = s0[j]; sn[hf][j + 4] = s1[j];
            }
        }
#pragma unroll
        for (int dc0 = 0; dc0 < 2; ++dc0)
#pragma unroll
            for (int j = 0; j < 8; ++j) {
                float c = cs[dc0][j], s2 = sn[dc0][j];
                float x1 = qv[dc0][j], x2 = qv[dc0 + 2][j];
                qv[dc0][j] = x1 * c - x2 * s2;
                qv[dc0 + 2][j] = x2 * c + x1 * s2;
            }
#pragma unroll
        for (int dc = 0; dc < 4; ++dc)
#pragma unroll
            for (int j = 0; j < 8; ++j) {
                float v = qv[dc][j] * SCL;
                u16 hb = f2bf(v);
                aqh[dc][j] = bfbits(hb);
                aql[dc][j] = bfbits(f2bf(v - bf2f(hb)));
            }
    }
    f32x4 oacc[8] = {};
    float m = -1e30f, l = 0.f;
    int NT = 2 * bx + 2;
    stageK(0);
    stageV(0, 0);
    asm volatile("s_waitcnt vmcnt(0)" ::: "memory");
    __syncthreads();
    int cur = 0;
    for (int kt = 0; kt < NT; ++kt) {
        int k0 = kt * 64;
        if (kt + 1 < NT) stageV(kt + 1, cur ^ 1);
        f32x4 s[4] = {};
        __builtin_amdgcn_s_setprio(1);
#pragma unroll
        for (int c = 0; c < 4; ++c) {
            if (k0 + c * 16 <= q_hi) {
                f32x4 a = {};
#pragma unroll
                for (int dc = 0; dc < 4; ++dc) {
                    bf16x8 kh8 = *(const bf16x8*)&smem[((c * 4 + dc) * 64 + lane) * 8];
                    bf16x8 kl8 =
                        *(const bf16x8*)&smem[8192 + ((c * 4 + dc) * 64 + lane) * 8];
                    a = __builtin_amdgcn_mfma_f32_16x16x32_bf16(kh8, aqh[dc], a, 0, 0, 0);
                    a = __builtin_amdgcn_mfma_f32_16x16x32_bf16(kh8, aql[dc], a, 0, 0, 0);
                    a = __builtin_amdgcn_mfma_f32_16x16x32_bf16(kl8, aqh[dc], a, 0, 0, 0);
                }
                s[c] = a;
            }
        }
        __builtin_amdgcn_s_setprio(0);
        __syncthreads();
        if (kt + 1 < NT) stageK(kt + 1);
        int q = q0 + lr;
        float tmax = -1e30f;
#pragma unroll
        for (int c = 0; c < 4; ++c) {
            bool active = (k0 + c * 16 <= q_hi);
            bool edge = (k0 + c * 16 + 15 >= q0);
#pragma unroll
            for (int r = 0; r < 4; ++r) {
                float sv = active ? s[c][r] : -1e30f;
                if (active && edge) {
                    int key = k0 + c * 16 + lc * 4 + r;
                    if (key > q) sv = -1e30f;
                }
                s[c][r] = sv;
                tmax = fmaxf(tmax, sv);
            }
        }
        tmax = fmaxf(tmax, __shfl_xor(tmax, 16));
        tmax = fmaxf(tmax, __shfl_xor(tmax, 32));
        if (__any(tmax > m + 8.0f)) {
            float mn = fmaxf(m, tmax);
            float alpha = exp2f(m - mn);
            m = mn;
            l *= alpha;
            float a0 = __shfl(alpha, lc * 4 + 0);
            float a1 = __shfl(alpha, lc * 4 + 1);
            float a2 = __shfl(alpha, lc * 4 + 2);
            float a3 = __shfl(alpha, lc * 4 + 3);
#pragma unroll
            for (int n = 0; n < 8; ++n) {
                oacc[n][0] *= a0; oacc[n][1] *= a1;
                oacc[n][2] *= a2; oacc[n][3] *= a3;
            }
        }
        float pvv[4][4];
        float psum = 0.f;
#pragma unroll
        for (int c = 0; c < 4; ++c)
#pragma unroll
            for (int r = 0; r < 4; ++r) {
                float pv = __builtin_amdgcn_exp2f(s[c][r] - m);
                pvv[c][r] = pv;
                psum += pv;
            }
        psum += __shfl_xor(psum, 16);
        psum += __shfl_xor(psum, 32);
        l += psum;
#pragma unroll
        for (int kc = 0; kc < 2; ++kc) {
            if (k0 + kc * 32 <= q_hi) {
                u32x2 w0, w1;
                w0[0] = __builtin_bit_cast(unsigned int,
                        __builtin_amdgcn_cvt_pkrtz(pvv[kc * 2][0], pvv[kc * 2][1]));
                w0[1] = __builtin_bit_cast(unsigned int,
                        __builtin_amdgcn_cvt_pkrtz(pvv[kc * 2][2], pvv[kc * 2][3]));
                w1[0] = __builtin_bit_cast(unsigned int,
                        __builtin_amdgcn_cvt_pkrtz(pvv[kc * 2 + 1][0], pvv[kc * 2 + 1][1]));
                w1[1] = __builtin_bit_cast(unsigned int,
                        __builtin_amdgcn_cvt_pkrtz(pvv[kc * 2 + 1][2], pvv[kc * 2 + 1][3]));
                *(u32x2*)&pb[lr * 40 + lc * 4] = w0;
                *(u32x2*)&pb[lr * 40 + 16 + lc * 4] = w1;
                asm volatile("s_waitcnt lgkmcnt(0)" ::: "memory");
                f16x8 pa = *(const f16x8*)&pb[lr * 40 + lc * 8];
                __builtin_amdgcn_s_setprio(1);
#pragma unroll
                for (int n = 0; n < 8; ++n) {
                    f16x8 v8 = *(const f16x8*)&smem[16384 + cur * 8192 +
                                                    ((kc * 8 + n) * 64 + lane) * 8];
                    oacc[n] = __builtin_amdgcn_mfma_f32_16x16x32_f16(pa, v8, oacc[n], 0, 0, 0);
                }
                __builtin_amdgcn_s_setprio(0);
            }
        }
        asm volatile("s_waitcnt vmcnt(0)" ::: "memory");
        __syncthreads();
        cur ^= 1;
    }
    float l0 = __shfl(l, lc * 4 + 0);
    float l1 = __shfl(l, lc * 4 + 1);
    float l2 = __shfl(l, lc * 4 + 2);
    float l3 = __shfl(l, lc * 4 + 3);
#pragma unroll
    for (int n = 0; n < 8; ++n) {
        int col = h * HD + n * 16 + lr;
        qf[(size_t)(q0 + lc * 4 + 0) * HID + col] = oacc[n][0] / l0;
        qf[(size_t)(q0 + lc * 4 + 1) * HID + col] = oacc[n][1] / l1;
        qf[(size_t)(q0 + lc * 4 + 2) * HID + col] = oacc[n][2] / l2;
        qf[(size_t)(q0 + lc * 4 + 3) * HID + col] = oacc[n][3] / l3;
    }
}

// ------- Hadamard head-mix (register FWHT) + int4 requant + wo pack ---------
__global__ __launch_bounds__(256) void k_hadq(const float* __restrict__ attn,
        s8* __restrict__ a2, float* __restrict__ sa,
        const int* __restrict__ wo, s8* __restrict__ wo8) {
    int t = blockIdx.x, tid = threadIdx.x;
    {
        size_t u0 = ((size_t)t * 256 + tid) * 2;
#pragma unroll
        for (int k = 0; k < 2; ++k) {
            size_t i = (u0 + k) * 16;
            i32x4 o;
#pragma unroll
            for (int j = 0; j < 4; ++j) {
                i32x4 v = *(const i32x4*)(wo + i + j * 4);
                o[j] = (v[0] & 0xff) | ((v[1] & 0xff) << 8) |
                       ((v[2] & 0xff) << 16) | (v[3] << 24);
            }
            *(i32x4*)(wo8 + i) = o;
        }
    }
    int w = tid >> 6, lane = tid & 63;
    int d = (w & 1) * 64 + lane;
    int half = w >> 1;
    __shared__ float rowb[HID];
    const float* ar = attn + (size_t)t * HID;
#pragma unroll
    for (int i = 0; i < 4; ++i)
        *(f32x4*)&rowb[i * 1024 + tid * 4] = *(const f32x4*)(ar + i * 1024 + tid * 4);
    __syncthreads();
    float u[16];
#pragma unroll
    for (int i = 0; i < 16; ++i) u[i] = rowb[(half * 16 + i) * 128 + d];
#pragma unroll
    for (int s = 1; s < 16; s <<= 1)
#pragma unroll
        for (int i = 0; i < 16; ++i)
            if (!(i & s)) {
                float a = u[i], b = u[i | s];
                u[i] = a + b;
                u[i | s] = a - b;
            }
#pragma unroll
    for (int i = 0; i < 16; ++i) rowb[(half * 16 + i) * 128 + d] = u[i];
    __syncthreads();
    float y[16], amax = 0.f;
#pragma unroll
    for (int i = 0; i < 16; ++i) {
        float o = rowb[((half ^ 1) * 16 + i) * 128 + d];
        float yv = half ? (o - u[i]) : (u[i] + o);
        yv *= 0.17677669529663687f;
        y[i] = yv;
        amax = fmaxf(amax, fabsf(yv));
    }
#pragma unroll
    for (int off = 32; off >= 1; off >>= 1)
        amax = fmaxf(amax, __shfl_xor(amax, off));
    __shared__ float red[4];
    if ((tid & 63) == 0) red[tid >> 6] = amax;
    __syncthreads();
    amax = fmaxf(fmaxf(red[0], red[1]), fmaxf(red[2], red[3]));
    float s = fmaxf(amax / 7.f, 1e-8f);
    if (tid == 0) sa[t] = s;
    s8* o2 = a2 + (size_t)t * HID;
#pragma unroll
    for (int i = 0; i < 16; ++i) {
        float q = rintf(y[i] / s);
        q = fminf(fmaxf(q, -8.f), 7.f);
        o2[(half * 16 + i) * 128 + d] = (s8)(int)q;
    }
}

extern "C" void kernel_launch(void* const* d_in, const int* in_sizes, int n_in,
                              void* d_out, int out_size, void* d_ws, size_t ws_size,
                              hipStream_t stream) {
    const int* positions = (const int*)d_in[0];
    const float* hidden = (const float*)d_in[1];
    const int* wq = (const int*)d_in[2];
    const float* wq_s = (const float*)d_in[3];
    const int* wk = (const int*)d_in[4];
    const float* wk_s = (const float*)d_in[5];
    const int* wv = (const int*)d_in[6];
    const float* wv_s = (const float*)d_in[7];
    const int* wo = (const int*)d_in[8];
    const float* wo_s = (const float*)d_in[9];

    char* ws = (char*)d_ws;
    float* s_x = (float*)(ws);
    float* s_a = (float*)(ws + 8192);
    float* ctab = (float*)(ws + 16384);
    float* stab = (float*)(ws + 16384 + 524288);
    char* base1 = ws + 16384 + 1048576;
    s8* a8 = (s8*)base1;                                 // 8.39 MB
    float* q_f = (float*)(base1 + 8388608);              // 33.55 MB
    float* k_f = (float*)(base1 + 8388608 + 33554432);   // 8.39 MB
    char* X = base1 + 8388608 + 33554432 + 8388608;      // 16.78 MB
    char* W2 = X + 16777216;                             // 8.39 MB
    s8* wq8 = (s8*)X;                 // dead after QKV-GEMM
    u16* khf = (u16*)(X);             // written by ropek (after QKV-GEMM)
    u16* klf = (u16*)(X + 4194304);
    u16* vf = (u16*)(X + 8388608);    // fp16 frag V^T, written by QKV-GEMM
    s8* wk8 = (s8*)W2;
    s8* wv8 = (s8*)(W2 + 4194304);
    s8* wo8 = (s8*)X;                 // packed by k_hadq after attn

    k_pre<<<8704, 256, 0, stream>>>(positions, hidden, wq, wk, wv, ctab, stab,
                                    a8, s_x, wq8, wk8, wv8);
    k_qkv<<<dim3(16, 48), 256, 0, stream>>>(a8, wq8, wk8, wv8, s_x,
                                            wq_s, wk_s, wv_s, q_f, k_f, vf);
    k_ropek<<<T_SEQ, 256, 0, stream>>>(k_f, ctab, stab, khf, klf);
    k_attn<<<512, 512, 0, stream>>>(q_f, khf, klf, vf, ctab, stab);
    k_hadq<<<T_SEQ, 256, 0, stream>>>(q_f, a8, s_a, wo, wo8);
    k_gemm8<<<dim3(16, 32), 256, 0, stream>>>(a8, wo8, s_a, wo_s,
                                              (float*)d_out);
}

// Round 12
// 253.650 us; speedup vs baseline: 1.1111x; 1.1111x over previous
//
#include <hip/hip_runtime.h>

#define T_SEQ 2048
#define HID 4096
#define NH 32
#define NKV 8
#define HD 128
#define KDIM 4096

typedef unsigned short u16;
typedef signed char s8;
typedef __attribute__((ext_vector_type(4))) float f32x4;
typedef __attribute__((ext_vector_type(4))) int i32x4;
typedef __attribute__((ext_vector_type(2))) unsigned int u32x2;
typedef __attribute__((ext_vector_type(8))) short s16x8;
typedef __attribute__((ext_vector_type(4))) short s16x4;
typedef __attribute__((ext_vector_type(8))) __bf16 bf16x8;
typedef __attribute__((ext_vector_type(8))) _Float16 f16x8;

static __device__ __forceinline__ u16 f2bf(float f) {
    __bf16 b = (__bf16)f;
    return __builtin_bit_cast(unsigned short, b);
}
static __device__ __forceinline__ float bf2f(u16 b) {
    unsigned u = ((unsigned)b) << 16;
    return __builtin_bit_cast(float, u);
}
static __device__ __forceinline__ __bf16 bfbits(u16 b) {
    return __builtin_bit_cast(__bf16, b);
}
static __device__ __forceinline__ u16 f2h(float f) {
    _Float16 h = (_Float16)f;
    return __builtin_bit_cast(unsigned short, h);
}

typedef __attribute__((address_space(1))) const void gas_t;
typedef __attribute__((address_space(3))) void las_t;
static __device__ __forceinline__ void gll16(const void* g, void* l) {
    __builtin_amdgcn_global_load_lds((gas_t*)g, (las_t*)l, 16, 0, 0);
}

// ---- fused pre-pass: trig tables | activation int4-quant | QKV weight pack --
__global__ __launch_bounds__(256) void k_pre(const int* __restrict__ pos,
        const float* __restrict__ x, const int* __restrict__ wq,
        const int* __restrict__ wk, const int* __restrict__ wv,
        float* __restrict__ ctab, float* __restrict__ stab,
        s8* __restrict__ a8, float* __restrict__ srow,
        s8* __restrict__ q8, s8* __restrict__ k8, s8* __restrict__ v8) {
    int b = blockIdx.x, tid = threadIdx.x;
    if (b < 512) {
        int idx = b * 256 + tid;
        int t = idx >> 6, d = idx & 63;
        float p = (float)pos[t];
        float inv = (float)pow(10000.0, -(double)d / 64.0);
        float ang = p * inv;
        double dsn, dcs;
        sincos((double)ang, &dsn, &dcs);
        ctab[idx] = (float)dcs;
        stab[idx] = (float)dsn;
    } else if (b < 512 + 2048) {
        int row = b - 512;
        const float* xr = x + (size_t)row * HID;
        f32x4 v[4];
        float amax = 0.f;
#pragma unroll
        for (int i = 0; i < 4; ++i) {
            v[i] = *(const f32x4*)(xr + i * 1024 + tid * 4);
#pragma unroll
            for (int j = 0; j < 4; ++j) amax = fmaxf(amax, fabsf(v[i][j]));
        }
#pragma unroll
        for (int off = 32; off >= 1; off >>= 1)
            amax = fmaxf(amax, __shfl_xor(amax, off));
        __shared__ float red[4];
        if ((tid & 63) == 0) red[tid >> 6] = amax;
        __syncthreads();
        amax = fmaxf(fmaxf(red[0], red[1]), fmaxf(red[2], red[3]));
        float s = fmaxf(amax / 7.f, 1e-8f);
        if (tid == 0) srow[row] = s;
        int* qr = (int*)(a8 + (size_t)row * HID);
#pragma unroll
        for (int i = 0; i < 4; ++i) {
            int p = 0;
#pragma unroll
            for (int j = 0; j < 4; ++j) {
                float q = rintf(v[i][j] / s);
                q = fminf(fmaxf(q, -8.f), 7.f);
                p |= ((int)q & 0xff) << (8 * j);
            }
            qr[i * 256 + tid] = p;
        }
    } else {
        size_t i = ((size_t)(b - 2560) * 256 + tid) * 16;
        const int* src; s8* dst; size_t off;
        if (i < 16777216) { src = wq; dst = q8; off = i; }
        else if (i < 20971520) { src = wk; dst = k8; off = i - 16777216; }
        else { src = wv; dst = v8; off = i - 20971520; }
        i32x4 o;
#pragma unroll
        for (int j = 0; j < 4; ++j) {
            i32x4 v = *(const i32x4*)(src + off + j * 4);
            o[j] = (v[0] & 0xff) | ((v[1] & 0xff) << 8) |
                   ((v[2] & 0xff) << 16) | (v[3] << 24);
        }
        *(i32x4*)(dst + off) = o;
    }
}

// ---------------- unified QKV int8 GEMM (16x16x64), dbuf pipeline -----------
// by in [0,32): Q -> q_f (f32). by in [32,40): K -> fused RoPE -> khf/klf frag.
// by in [40,48): V -> vf (fragment-ordered fp16 V^T).
__global__ __launch_bounds__(256) void k_qkv(const s8* __restrict__ A,
        const s8* __restrict__ Wq, const s8* __restrict__ Wk,
        const s8* __restrict__ Wv, const float* __restrict__ sRow,
        const float* __restrict__ sq, const float* __restrict__ sk,
        const float* __restrict__ sv, float* __restrict__ qout,
        u16* __restrict__ voutf, u16* __restrict__ khf,
        u16* __restrict__ klf, const float* __restrict__ ctab,
        const float* __restrict__ stab) {
    __shared__ __align__(16) s8 smem[66560];  // dbuf 64KB; K-epi f32 [128][129]
    int tid = threadIdx.x;
    int by = blockIdx.y;
    int mode = by < 32 ? 0 : (by < 40 ? 1 : 2);
    const s8* W = mode == 0 ? Wq : (mode == 1 ? Wk : Wv);
    const float* sCol = mode == 0 ? sq : (mode == 1 ? sk : sv);
    int bcolb = mode == 0 ? by : (mode == 1 ? by - 32 : by - 40);
    int brow = blockIdx.x * 128, bcol = bcolb * 128;
    const int K = KDIM;
    int wid = tid >> 6, lane = tid & 63;
    int wr = (wid >> 1) * 64, wc = (wid & 1) * 64;
    int lr = lane & 15, lc = lane >> 4;
    i32x4 acc[4][4] = {};
    auto stage = [&](int buf, int k0) {
#pragma unroll
        for (int j = 0; j < 4; ++j) {
            int base = wid * 1024 + j * 4096;
            int o = base + lane * 16;
            int r = o >> 7;
            int c = (o & 127) ^ ((r & 7) << 4);
            gll16(A + (size_t)(brow + r) * K + (k0 + c),
                  (char*)smem + buf * 16384 + base);
            gll16(W + (size_t)(bcol + r) * K + (k0 + c),
                  (char*)smem + 32768 + buf * 16384 + base);
        }
    };
    stage(0, 0);
    asm volatile("s_waitcnt vmcnt(0)" ::: "memory");
    __syncthreads();
    int cur = 0;
    for (int k0 = 0; k0 < K; k0 += 128) {
        if (k0 + 128 < K) stage(cur ^ 1, k0 + 128);
        const s8* sAc = (const s8*)smem + cur * 16384;
        const s8* sBc = (const s8*)smem + 32768 + cur * 16384;
#pragma unroll
        for (int kk = 0; kk < 2; ++kk) {
            i32x4 af[4], bf[4];
#pragma unroll
            for (int m = 0; m < 4; ++m) {
                int r = wr + m * 16 + lr;
                int sl = ((kk * 4 + lc) ^ (r & 7)) * 16;
                af[m] = *(const i32x4*)&sAc[r * 128 + sl];
            }
#pragma unroll
            for (int n = 0; n < 4; ++n) {
                int r = wc + n * 16 + lr;
                int sl = ((kk * 4 + lc) ^ (r & 7)) * 16;
                bf[n] = *(const i32x4*)&sBc[r * 128 + sl];
            }
#pragma unroll
            for (int m = 0; m < 4; ++m)
#pragma unroll
                for (int n = 0; n < 4; ++n)
                    acc[m][n] = __builtin_amdgcn_mfma_i32_16x16x64_i8(
                        af[m], bf[n], acc[m][n], 0, 0, 0);
        }
        asm volatile("s_waitcnt vmcnt(0)" ::: "memory");
        __syncthreads();
        cur ^= 1;
    }
    if (mode == 0) {
#pragma unroll
        for (int m = 0; m < 4; ++m) {
            int row0 = brow + wr + m * 16 + lc * 4;
#pragma unroll
            for (int n = 0; n < 4; ++n) {
                int col = bcol + wc + n * 16 + lr;
                float scl = sCol[col];
#pragma unroll
                for (int r = 0; r < 4; ++r)
                    qout[(size_t)(row0 + r) * HID + col] =
                        (float)acc[m][n][r] * sRow[row0 + r] * scl;
            }
        }
    } else if (mode == 2) {
#pragma unroll
        for (int m = 0; m < 4; ++m) {
            int row0 = brow + wr + m * 16 + lc * 4;
#pragma unroll
            for (int n = 0; n < 4; ++n) {
                int col = bcol + wc + n * 16 + lr;
                float scl = sCol[col];
                int kvh = col >> 7, d = col & 127;
                int nn = d >> 4, lrv = d & 15;
                int kt = row0 >> 6, rem = row0 & 63;
                int kc = rem >> 5, lcv = (rem & 31) >> 3, j0 = rem & 7;
                size_t base =
                    ((((size_t)(kvh * 32 + kt) * 2 + kc) * 8 + nn) * 64 +
                     lcv * 16 + lrv) * 8 + j0;
                s16x4 hh;
#pragma unroll
                for (int r = 0; r < 4; ++r) {
                    float val = (float)acc[m][n][r] * sRow[row0 + r] * scl;
                    hh[r] = (short)f2h(val);
                }
                *(s16x4*)(voutf + base) = hh;
            }
        }
    } else {
        // ---- fused K-RoPE epilogue: scaled f32 tile -> LDS -> rotate ->
        //      fragment-ordered hi/lo bf16 (bit-identical to old k_f+ropek) --
        float* T = (float*)smem;  // [128][129] padded
#pragma unroll
        for (int m = 0; m < 4; ++m) {
            int rl0 = wr + m * 16 + lc * 4;
#pragma unroll
            for (int n = 0; n < 4; ++n) {
                int cl = wc + n * 16 + lr;
                float scl = sCol[bcol + cl];
#pragma unroll
                for (int r = 0; r < 4; ++r)
                    T[(rl0 + r) * 129 + cl] =
                        (float)acc[m][n][r] * sRow[brow + rl0 + r] * scl;
            }
        }
        __syncthreads();
        int kvh = bcolb;
#pragma unroll
        for (int p = 0; p < 32; ++p) {
            int idx = p * 256 + tid;
            int row = idx >> 6, d = idx & 63;
            int t = brow + row;
            float cs = ctab[t * 64 + d], sn = stab[t * 64 + d];
            float x1 = T[row * 129 + d], x2 = T[row * 129 + 64 + d];
            float r1 = x1 * cs - x2 * sn;
            float r2 = x2 * cs + x1 * sn;
            int kt2 = t >> 6, rem = t & 63, cblk = rem >> 4, lrk = rem & 15;
            size_t tb = (((size_t)(kvh * 32 + kt2) * 4 + cblk) * 4) * 512;
#pragma unroll
            for (int half = 0; half < 2; ++half) {
                int x = d + half * 64;
                float rv = half ? r2 : r1;
                int dcx = x >> 5, lcx = (x & 31) >> 3, jx = x & 7;
                size_t ii = tb + (size_t)dcx * 512 + (lcx * 16 + lrk) * 8 + jx;
                u16 hb = f2bf(rv);
                khf[ii] = hb;
                klf[ii] = f2bf(rv - bf2f(hb));
            }
        }
    }
}

// ---------------- O-proj int8 GEMM (16x16x64), dbuf pipeline ----------------
__global__ __launch_bounds__(256) void k_gemm8(const s8* __restrict__ A,
        const s8* __restrict__ W, const float* __restrict__ sRow,
        const float* __restrict__ sCol, float* __restrict__ outp) {
    __shared__ __align__(16) s8 sA[2][16384], sB[2][16384];
    int tid = threadIdx.x;
    int brow = blockIdx.x * 128, bcol = blockIdx.y * 128;
    const int K = KDIM;
    int wid = tid >> 6, lane = tid & 63;
    int wr = (wid >> 1) * 64, wc = (wid & 1) * 64;
    int lr = lane & 15, lc = lane >> 4;
    i32x4 acc[4][4] = {};
    auto stage = [&](int buf, int k0) {
#pragma unroll
        for (int j = 0; j < 4; ++j) {
            int base = wid * 1024 + j * 4096;
            int o = base + lane * 16;
            int r = o >> 7;
            int c = (o & 127) ^ ((r & 7) << 4);
            gll16(A + (size_t)(brow + r) * K + (k0 + c), (char*)sA[buf] + base);
            gll16(W + (size_t)(bcol + r) * K + (k0 + c), (char*)sB[buf] + base);
        }
    };
    stage(0, 0);
    asm volatile("s_waitcnt vmcnt(0)" ::: "memory");
    __syncthreads();
    int cur = 0;
    for (int k0 = 0; k0 < K; k0 += 128) {
        if (k0 + 128 < K) stage(cur ^ 1, k0 + 128);
#pragma unroll
        for (int kk = 0; kk < 2; ++kk) {
            i32x4 af[4], bf[4];
#pragma unroll
            for (int m = 0; m < 4; ++m) {
                int r = wr + m * 16 + lr;
                int sl = ((kk * 4 + lc) ^ (r & 7)) * 16;
                af[m] = *(const i32x4*)&sA[cur][r * 128 + sl];
            }
#pragma unroll
            for (int n = 0; n < 4; ++n) {
                int r = wc + n * 16 + lr;
                int sl = ((kk * 4 + lc) ^ (r & 7)) * 16;
                bf[n] = *(const i32x4*)&sB[cur][r * 128 + sl];
            }
#pragma unroll
            for (int m = 0; m < 4; ++m)
#pragma unroll
                for (int n = 0; n < 4; ++n)
                    acc[m][n] = __builtin_amdgcn_mfma_i32_16x16x64_i8(
                        af[m], bf[n], acc[m][n], 0, 0, 0);
        }
        asm volatile("s_waitcnt vmcnt(0)" ::: "memory");
        __syncthreads();
        cur ^= 1;
    }
#pragma unroll
    for (int m = 0; m < 4; ++m) {
        int row0 = brow + wr + m * 16 + lc * 4;
#pragma unroll
        for (int n = 0; n < 4; ++n) {
            int col = bcol + wc + n * 16 + lr;
            float scl = sCol[col];
#pragma unroll
            for (int r = 0; r < 4; ++r)
                outp[(size_t)(row0 + r) * HID + col] =
                    (float)acc[m][n][r] * sRow[row0 + r] * scl;
        }
    }
}

// ---------------- GQA causal flash attention (unchanged from R10) ------------
__global__ __launch_bounds__(512, 4) void k_attn(float* __restrict__ qf,
        const u16* __restrict__ khf, const u16* __restrict__ klf,
        const u16* __restrict__ vf,
        const float* __restrict__ ctab, const float* __restrict__ stab) {
    int bid = blockIdx.x;
    int kvh = bid & 7;
    int h = kvh * 4 + ((bid >> 3) & 3);
    int sidx = bid >> 5;
    int bx = sidx < 8 ? sidx : 23 - sidx;
    int tid = threadIdx.x, wid = tid >> 6, lane = tid & 63;
    int lr = lane & 15, lc = lane >> 4;
    int q0 = bx * 128 + wid * 16, q_hi = q0 + 15;
    __shared__ __align__(16) u16 smem[37888];
    u16* pb = smem + 32768 + wid * 640;
    const float SCL = 0.12751744f;
    size_t kvbase = (size_t)kvh * 32 * 8192;
    auto stageK = [&](int kt) {
        const char* gk = (const char*)(khf + kvbase + (size_t)kt * 8192);
        const char* gl = (const char*)(klf + kvbase + (size_t)kt * 8192);
#pragma unroll
        for (int j = 0; j < 4; ++j) {
            int c = wid * 4 + j;
            int sel = c >> 4;
            int inner = (c & 15) * 1024;
            gll16((sel ? gl : gk) + inner + lane * 16,
                  (char*)smem + sel * 16384 + inner);
        }
    };
    auto stageV = [&](int kt, int buf) {
        const char* gv = (const char*)(vf + kvbase + (size_t)kt * 8192);
#pragma unroll
        for (int j = 0; j < 2; ++j) {
            int c = wid * 2 + j;
            gll16(gv + c * 1024 + lane * 16,
                  (char*)smem + 32768 + buf * 16384 + c * 1024);
        }
    };
    bf16x8 aqh[4], aql[4];
    {
        const float* qrow = qf + (size_t)(q0 + lr) * HID + h * HD;
        const float* ct = ctab + (size_t)(q0 + lr) * 64 + lc * 8;
        const float* st = stab + (size_t)(q0 + lr) * 64 + lc * 8;
        float qv[4][8];
#pragma unroll
        for (int dc = 0; dc < 4; ++dc) {
            f32x4 a = *(const f32x4*)(qrow + dc * 32 + lc * 8);
            f32x4 b = *(const f32x4*)(qrow + dc * 32 + lc * 8 + 4);
#pragma unroll
            for (int j = 0; j < 4; ++j) { qv[dc][j] = a[j]; qv[dc][j + 4] = b[j]; }
        }
        float cs[2][8], sn[2][8];
#pragma unroll
        for (int hf = 0; hf < 2; ++hf) {
            f32x4 c0 = *(const f32x4*)(ct + hf * 32);
            f32x4 c1 = *(const f32x4*)(ct + hf * 32 + 4);
            f32x4 s0 = *(const f32x4*)(st + hf * 32);
            f32x4 s1 = *(const f32x4*)(st + hf * 32 + 4);
#pragma unroll
            for (int j = 0; j < 4; ++j) {
                cs[hf][j] = c0[j]; cs[hf][j + 4] = c1[j];
                sn[hf][j] = s0[j]; sn[hf][j + 4] = s1[j];
            }
        }
#pragma unroll
        for (int dc0 = 0; dc0 < 2; ++dc0)
#pragma unroll
            for (int j = 0; j < 8; ++j) {
                float c = cs[dc0][j], s2 = sn[dc0][j];
                float x1 = qv[dc0][j], x2 = qv[dc0 + 2][j];
                qv[dc0][j] = x1 * c - x2 * s2;
                qv[dc0 + 2][j] = x2 * c + x1 * s2;
            }
#pragma unroll
        for (int dc = 0; dc < 4; ++dc)
#pragma unroll
            for (int j = 0; j < 8; ++j) {
                float v = qv[dc][j] * SCL;
                u16 hb = f2bf(v);
                aqh[dc][j] = bfbits(hb);
                aql[dc][j] = bfbits(f2bf(v - bf2f(hb)));
            }
    }
    f32x4 oacc[8] = {};
    float m = -1e30f, l = 0.f;
    int NT = 2 * bx + 2;
    stageK(0);
    stageV(0, 0);
    asm volatile("s_waitcnt vmcnt(0)" ::: "memory");
    __syncthreads();
    int cur = 0;
    for (int kt = 0; kt < NT; ++kt) {
        int k0 = kt * 64;
        if (kt + 1 < NT) stageV(kt + 1, cur ^ 1);
        f32x4 s[4] = {};
        __builtin_amdgcn_s_setprio(1);
#pragma unroll
        for (int c = 0; c < 4; ++c) {
            if (k0 + c * 16 <= q_hi) {
                f32x4 a = {};
#pragma unroll
                for (int dc = 0; dc < 4; ++dc) {
                    bf16x8 kh8 = *(const bf16x8*)&smem[((c * 4 + dc) * 64 + lane) * 8];
                    bf16x8 kl8 =
                        *(const bf16x8*)&smem[8192 + ((c * 4 + dc) * 64 + lane) * 8];
                    a = __builtin_amdgcn_mfma_f32_16x16x32_bf16(kh8, aqh[dc], a, 0, 0, 0);
                    a = __builtin_amdgcn_mfma_f32_16x16x32_bf16(kh8, aql[dc], a, 0, 0, 0);
                    a = __builtin_amdgcn_mfma_f32_16x16x32_bf16(kl8, aqh[dc], a, 0, 0, 0);
                }
                s[c] = a;
            }
        }
        __builtin_amdgcn_s_setprio(0);
        __syncthreads();
        if (kt + 1 < NT) stageK(kt + 1);
        int q = q0 + lr;
        float tmax = -1e30f;
#pragma unroll
        for (int c = 0; c < 4; ++c) {
            bool active = (k0 + c * 16 <= q_hi);
            bool edge = (k0 + c * 16 + 15 >= q0);
#pragma unroll
            for (int r = 0; r < 4; ++r) {
                float sv = active ? s[c][r] : -1e30f;
                if (active && edge) {
                    int key = k0 + c * 16 + lc * 4 + r;
                    if (key > q) sv = -1e30f;
                }
                s[c][r] = sv;
                tmax = fmaxf(tmax, sv);
            }
        }
        tmax = fmaxf(tmax, __shfl_xor(tmax, 16));
        tmax = fmaxf(tmax, __shfl_xor(tmax, 32));
        if (__any(tmax > m + 8.0f)) {
            float mn = fmaxf(m, tmax);
            float alpha = exp2f(m - mn);
            m = mn;
            l *= alpha;
            float a0 = __shfl(alpha, lc * 4 + 0);
            float a1 = __shfl(alpha, lc * 4 + 1);
            float a2 = __shfl(alpha, lc * 4 + 2);
            float a3 = __shfl(alpha, lc * 4 + 3);
#pragma unroll
            for (int n = 0; n < 8; ++n) {
                oacc[n][0] *= a0; oacc[n][1] *= a1;
                oacc[n][2] *= a2; oacc[n][3] *= a3;
            }
        }
        float pvv[4][4];
        float psum = 0.f;
#pragma unroll
        for (int c = 0; c < 4; ++c)
#pragma unroll
            for (int r = 0; r < 4; ++r) {
                float pv = __builtin_amdgcn_exp2f(s[c][r] - m);
                pvv[c][r] = pv;
                psum += pv;
            }
        psum += __shfl_xor(psum, 16);
        psum += __shfl_xor(psum, 32);
        l += psum;
#pragma unroll
        for (int kc = 0; kc < 2; ++kc) {
            if (k0 + kc * 32 <= q_hi) {
                u32x2 w0, w1;
                w0[0] = __builtin_bit_cast(unsigned int,
                        __builtin_amdgcn_cvt_pkrtz(pvv[kc * 2][0], pvv[kc * 2][1]));
                w0[1] = __builtin_bit_cast(unsigned int,
                        __builtin_amdgcn_cvt_pkrtz(pvv[kc * 2][2], pvv[kc * 2][3]));
                w1[0] = __builtin_bit_cast(unsigned int,
                        __builtin_amdgcn_cvt_pkrtz(pvv[kc * 2 + 1][0], pvv[kc * 2 + 1][1]));
                w1[1] = __builtin_bit_cast(unsigned int,
                        __builtin_amdgcn_cvt_pkrtz(pvv[kc * 2 + 1][2], pvv[kc * 2 + 1][3]));
                *(u32x2*)&pb[lr * 40 + lc * 4] = w0;
                *(u32x2*)&pb[lr * 40 + 16 + lc * 4] = w1;
                asm volatile("s_waitcnt lgkmcnt(0)" ::: "memory");
                f16x8 pa = *(const f16x8*)&pb[lr * 40 + lc * 8];
                __builtin_amdgcn_s_setprio(1);
#pragma unroll
                for (int n = 0; n < 8; ++n) {
                    f16x8 v8 = *(const f16x8*)&smem[16384 + cur * 8192 +
                                                    ((kc * 8 + n) * 64 + lane) * 8];
                    oacc[n] = __builtin_amdgcn_mfma_f32_16x16x32_f16(pa, v8, oacc[n], 0, 0, 0);
                }
                __builtin_amdgcn_s_setprio(0);
            }
        }
        asm volatile("s_waitcnt vmcnt(0)" ::: "memory");
        __syncthreads();
        cur ^= 1;
    }
    float l0 = __shfl(l, lc * 4 + 0);
    float l1 = __shfl(l, lc * 4 + 1);
    float l2 = __shfl(l, lc * 4 + 2);
    float l3 = __shfl(l, lc * 4 + 3);
#pragma unroll
    for (int n = 0; n < 8; ++n) {
        int col = h * HD + n * 16 + lr;
        qf[(size_t)(q0 + lc * 4 + 0) * HID + col] = oacc[n][0] / l0;
        qf[(size_t)(q0 + lc * 4 + 1) * HID + col] = oacc[n][1] / l1;
        qf[(size_t)(q0 + lc * 4 + 2) * HID + col] = oacc[n][2] / l2;
        qf[(size_t)(q0 + lc * 4 + 3) * HID + col] = oacc[n][3] / l3;
    }
}

// ------- Hadamard head-mix (register FWHT) + int4 requant + wo pack ---------
__global__ __launch_bounds__(256) void k_hadq(const float* __restrict__ attn,
        s8* __restrict__ a2, float* __restrict__ sa,
        const int* __restrict__ wo, s8* __restrict__ wo8) {
    int t = blockIdx.x, tid = threadIdx.x;
    {
        size_t u0 = ((size_t)t * 256 + tid) * 2;
#pragma unroll
        for (int k = 0; k < 2; ++k) {
            size_t i = (u0 + k) * 16;
            i32x4 o;
#pragma unroll
            for (int j = 0; j < 4; ++j) {
                i32x4 v = *(const i32x4*)(wo + i + j * 4);
                o[j] = (v[0] & 0xff) | ((v[1] & 0xff) << 8) |
                       ((v[2] & 0xff) << 16) | (v[3] << 24);
            }
            *(i32x4*)(wo8 + i) = o;
        }
    }
    int w = tid >> 6, lane = tid & 63;
    int d = (w & 1) * 64 + lane;
    int half = w >> 1;
    __shared__ float rowb[HID];
    const float* ar = attn + (size_t)t * HID;
#pragma unroll
    for (int i = 0; i < 4; ++i)
        *(f32x4*)&rowb[i * 1024 + tid * 4] = *(const f32x4*)(ar + i * 1024 + tid * 4);
    __syncthreads();
    float u[16];
#pragma unroll
    for (int i = 0; i < 16; ++i) u[i] = rowb[(half * 16 + i) * 128 + d];
#pragma unroll
    for (int s = 1; s < 16; s <<= 1)
#pragma unroll
        for (int i = 0; i < 16; ++i)
            if (!(i & s)) {
                float a = u[i], b = u[i | s];
                u[i] = a + b;
                u[i | s] = a - b;
            }
#pragma unroll
    for (int i = 0; i < 16; ++i) rowb[(half * 16 + i) * 128 + d] = u[i];
    __syncthreads();
    float y[16], amax = 0.f;
#pragma unroll
    for (int i = 0; i < 16; ++i) {
        float o = rowb[((half ^ 1) * 16 + i) * 128 + d];
        float yv = half ? (o - u[i]) : (u[i] + o);
        yv *= 0.17677669529663687f;
        y[i] = yv;
        amax = fmaxf(amax, fabsf(yv));
    }
#pragma unroll
    for (int off = 32; off >= 1; off >>= 1)
        amax = fmaxf(amax, __shfl_xor(amax, off));
    __shared__ float red[4];
    if ((tid & 63) == 0) red[tid >> 6] = amax;
    __syncthreads();
    amax = fmaxf(fmaxf(red[0], red[1]), fmaxf(red[2], red[3]));
    float s = fmaxf(amax / 7.f, 1e-8f);
    if (tid == 0) sa[t] = s;
    s8* o2 = a2 + (size_t)t * HID;
#pragma unroll
    for (int i = 0; i < 16; ++i) {
        float q = rintf(y[i] / s);
        q = fminf(fmaxf(q, -8.f), 7.f);
        o2[(half * 16 + i) * 128 + d] = (s8)(int)q;
    }
}

extern "C" void kernel_launch(void* const* d_in, const int* in_sizes, int n_in,
                              void* d_out, int out_size, void* d_ws, size_t ws_size,
                              hipStream_t stream) {
    const int* positions = (const int*)d_in[0];
    const float* hidden = (const float*)d_in[1];
    const int* wq = (const int*)d_in[2];
    const float* wq_s = (const float*)d_in[3];
    const int* wk = (const int*)d_in[4];
    const float* wk_s = (const float*)d_in[5];
    const int* wv = (const int*)d_in[6];
    const float* wv_s = (const float*)d_in[7];
    const int* wo = (const int*)d_in[8];
    const float* wo_s = (const float*)d_in[9];

    char* ws = (char*)d_ws;
    float* s_x = (float*)(ws);
    float* s_a = (float*)(ws + 8192);
    float* ctab = (float*)(ws + 16384);
    float* stab = (float*)(ws + 16384 + 524288);
    char* base1 = ws + 16384 + 1048576;
    s8* a8 = (s8*)base1;                                 // 8.39 MB
    float* q_f = (float*)(base1 + 8388608);              // 33.55 MB
    char* KHL = base1 + 8388608 + 33554432;              // 8.39 MB (old k_f)
    u16* khf = (u16*)(KHL);                              // frag K hi (fresh)
    u16* klf = (u16*)(KHL + 4194304);                    // frag K lo (fresh)
    char* X = base1 + 8388608 + 33554432 + 8388608;      // 16.78 MB
    char* W2 = X + 16777216;                             // 8.39 MB
    s8* wq8 = (s8*)X;                 // dead after QKV-GEMM
    u16* vf = (u16*)(X + 8388608);    // fp16 frag V^T (written by QKV-GEMM)
    s8* wk8 = (s8*)W2;
    s8* wv8 = (s8*)(W2 + 4194304);
    s8* wo8 = (s8*)X;                 // packed by k_hadq after attn

    k_pre<<<8704, 256, 0, stream>>>(positions, hidden, wq, wk, wv, ctab, stab,
                                    a8, s_x, wq8, wk8, wv8);
    k_qkv<<<dim3(16, 48), 256, 0, stream>>>(a8, wq8, wk8, wv8, s_x,
                                            wq_s, wk_s, wv_s, q_f, vf,
                                            khf, klf, ctab, stab);
    k_attn<<<512, 512, 0, stream>>>(q_f, khf, klf, vf, ctab, stab);
    k_hadq<<<T_SEQ, 256, 0, stream>>>(q_f, a8, s_a, wo, wo8);
    k_gemm8<<<dim3(16, 32), 256, 0, stream>>>(a8, wo8, s_a, wo_s,
                                              (float*)d_out);
}